// Round 1
// baseline (940.910 us; speedup 1.0000x reference)
//
#include <hip/hip_runtime.h>

typedef __attribute__((ext_vector_type(8))) short bf16x8;
typedef __attribute__((ext_vector_type(4))) float f32x4;

#define B_    32
#define CIN   1024
#define H_    37
#define W_    37
#define HP    39          // padded spatial
#define DIM   512
#define COUT  120
#define M1    43808       // B*H*W
#define LDT   40          // padded LDS row in bf16 elems (BK=32 + 8)

// fp32 -> bf16 round-to-nearest-even
__device__ __forceinline__ unsigned short f2bf(float f) {
    unsigned int u = __float_as_uint(f);
    unsigned int r = 0x7fffu + ((u >> 16) & 1u);
    return (unsigned short)((u + r) >> 16);
}

// ---------------------------------------------------------------------------
// K0: NCHW fp32 -> padded NHWC bf16  [32][39][39][1024], interior only
// (borders pre-zeroed by hipMemsetAsync). One block = (b, y, 256-ci tile).
// ---------------------------------------------------------------------------
__global__ __launch_bounds__(256) void pad_transpose(
    const float* __restrict__ fmap, unsigned short* __restrict__ nhwc)
{
    __shared__ float lds[37 * 257];  // [xx][cl], +1 pad breaks bank conflicts
    const int t = threadIdx.x;
    const int bid = blockIdx.x;
    const int citile = bid & 3;
    const int rest = bid >> 2;
    const int y = rest % 37;
    const int b = rest / 37;
    const int ci0 = citile * 256;

    const float* src = fmap + ((size_t)(b * CIN + ci0)) * (H_ * W_) + y * W_;
    #pragma unroll 1
    for (int k = 0; k < 37; ++k) {
        unsigned int flat = (unsigned)(k * 256 + t);   // = cl*37 + xx
        unsigned int cl = flat / 37u;
        unsigned int xx = flat - cl * 37u;
        lds[xx * 257 + cl] = src[(size_t)cl * (H_ * W_) + xx];
    }
    __syncthreads();
    unsigned short* dst = nhwc + ((size_t)(b * HP + y + 1) * HP + 1) * CIN + ci0;
    #pragma unroll 1
    for (int k = 0; k < 37; ++k) {
        unsigned int flat = (unsigned)(k * 256 + t);
        unsigned int xx = flat >> 8;       // /256
        unsigned int cl = flat & 255u;
        dst[(size_t)xx * CIN + cl] = f2bf(lds[xx * 257 + cl]);
    }
}

// ---------------------------------------------------------------------------
// K1: w1 [512][1024][3][3] fp32 -> [512][9][1024] bf16  (B^T, k=(kykx,ci))
// ---------------------------------------------------------------------------
__global__ __launch_bounds__(256) void reorder_w1(
    const float* __restrict__ w1, unsigned short* __restrict__ w1b)
{
    int g = blockIdx.x * 256 + threadIdx.x;
    if (g >= DIM * 9 * CIN) return;
    int n = g / (9 * CIN);
    int rem = g - n * (9 * CIN);
    int kykx = rem >> 10;
    int ci = rem & 1023;
    w1b[g] = f2bf(w1[((size_t)n * CIN + ci) * 9 + kykx]);
}

// ---------------------------------------------------------------------------
// K2: w2 [120][512] fp32 -> bf16 (layout already [n][k])
// ---------------------------------------------------------------------------
__global__ __launch_bounds__(256) void cast_w2(
    const float* __restrict__ w2, unsigned short* __restrict__ w2b)
{
    int g = blockIdx.x * 256 + threadIdx.x;
    if (g < COUT * DIM) w2b[g] = f2bf(w2[g]);
}

// ---------------------------------------------------------------------------
// K3: implicit GEMM conv3x3: M=43808, N=512, K=9216, BM=BN=128, BK=32
// A[m][k] = nhwc_pad[b][y+ky][x+kx][ci], B^T = w1b[n][kykx][ci]
// Fused: +b1, clip[0,6], store bf16 x1[m][512]
// ---------------------------------------------------------------------------
__global__ __launch_bounds__(256, 2) void conv1_gemm(
    const unsigned short* __restrict__ nhwc,
    const unsigned short* __restrict__ w1b,
    const float* __restrict__ b1,
    unsigned short* __restrict__ x1)
{
    __shared__ unsigned short aLds[128 * LDT];
    __shared__ unsigned short bLds[128 * LDT];

    const int t = threadIdx.x;
    const int mtile = blockIdx.x >> 2;     // 343 tiles
    const int ntile = blockIdx.x & 3;      // 4 tiles
    const int m0 = mtile * 128;
    const int n0 = ntile * 128;

    // staging: thread handles rows (t>>2) and 64+(t>>2), 16B segment t&3
    const int row0 = t >> 2;
    const int row1 = 64 + row0;
    const int seg = t & 3;

    int mA0 = m0 + row0; if (mA0 >= M1) mA0 = M1 - 1;
    int mA1 = m0 + row1; if (mA1 >= M1) mA1 = M1 - 1;
    int b0i = mA0 / 1369, rr0 = mA0 % 1369;
    int b1i = mA1 / 1369, rr1 = mA1 % 1369;
    const int pos0 = (b0i * HP + (rr0 / 37)) * HP + (rr0 % 37);
    const int pos1 = (b1i * HP + (rr1 / 37)) * HP + (rr1 % 37);

    const unsigned short* bRow0 = w1b + (size_t)(n0 + row0) * 9216 + seg * 8;
    const unsigned short* bRow1 = w1b + (size_t)(n0 + row1) * 9216 + seg * 8;

    const int lane = t & 63;
    const int wv = t >> 6;
    const int wm = wv & 1, wn = wv >> 1;
    const int lr = lane & 15, quad = lane >> 4;

    f32x4 acc[4][4];
    #pragma unroll
    for (int i = 0; i < 4; ++i)
        #pragma unroll
        for (int j = 0; j < 4; ++j)
            acc[i][j] = (f32x4){0.f, 0.f, 0.f, 0.f};

    unsigned short* aW0 = aLds + row0 * LDT + seg * 8;
    unsigned short* aW1 = aLds + row1 * LDT + seg * 8;
    unsigned short* bW0 = bLds + row0 * LDT + seg * 8;
    unsigned short* bW1 = bLds + row1 * LDT + seg * 8;

    for (int kykx = 0; kykx < 9; ++kykx) {
        const int ky = kykx / 3, kx = kykx - ky * 3;
        const unsigned short* aG0 = nhwc + (((size_t)(pos0 + ky * HP + kx)) << 10) + seg * 8;
        const unsigned short* aG1 = nhwc + (((size_t)(pos1 + ky * HP + kx)) << 10) + seg * 8;
        const unsigned short* bG0 = bRow0 + kykx * 1024;
        const unsigned short* bG1 = bRow1 + kykx * 1024;
        #pragma unroll 1
        for (int ci0 = 0; ci0 < 1024; ci0 += 32) {
            int4 va0 = *(const int4*)(aG0 + ci0);
            int4 va1 = *(const int4*)(aG1 + ci0);
            int4 vb0 = *(const int4*)(bG0 + ci0);
            int4 vb1 = *(const int4*)(bG1 + ci0);
            __syncthreads();
            *(int4*)aW0 = va0;
            *(int4*)aW1 = va1;
            *(int4*)bW0 = vb0;
            *(int4*)bW1 = vb1;
            __syncthreads();
            bf16x8 af[4], bfr[4];
            #pragma unroll
            for (int i = 0; i < 4; ++i)
                af[i] = *(const bf16x8*)(aLds + (wm * 64 + i * 16 + lr) * LDT + quad * 8);
            #pragma unroll
            for (int j = 0; j < 4; ++j)
                bfr[j] = *(const bf16x8*)(bLds + (wn * 64 + j * 16 + lr) * LDT + quad * 8);
            #pragma unroll
            for (int i = 0; i < 4; ++i)
                #pragma unroll
                for (int j = 0; j < 4; ++j)
                    acc[i][j] = __builtin_amdgcn_mfma_f32_16x16x32_bf16(
                        af[i], bfr[j], acc[i][j], 0, 0, 0);
        }
    }

    // epilogue: C/D layout col=lane&15, row=quad*4+reg
    #pragma unroll
    for (int i = 0; i < 4; ++i) {
        const int mloc = m0 + wm * 64 + i * 16 + quad * 4;
        #pragma unroll
        for (int j = 0; j < 4; ++j) {
            const int n = n0 + wn * 64 + j * 16 + lr;
            const float bias = b1[n];
            #pragma unroll
            for (int r = 0; r < 4; ++r) {
                const int m = mloc + r;
                if (m < M1) {
                    float v = acc[i][j][r] + bias;
                    v = fminf(fmaxf(v, 0.f), 6.f);
                    x1[(size_t)m * DIM + n] = f2bf(v);
                }
            }
        }
    }
}

// ---------------------------------------------------------------------------
// K4: GEMM conv1x1: M=43808, N=120 (tile 128 w/ guards), K=512
// out fp32 = x1 @ w2b^T + b2  -> d_out (NHWC-flat == reference order)
// ---------------------------------------------------------------------------
__global__ __launch_bounds__(256, 2) void conv2_gemm(
    const unsigned short* __restrict__ x1,
    const unsigned short* __restrict__ w2b,
    const float* __restrict__ b2,
    float* __restrict__ out)
{
    __shared__ unsigned short aLds[128 * LDT];
    __shared__ unsigned short bLds[128 * LDT];

    const int t = threadIdx.x;
    const int m0 = blockIdx.x * 128;

    const int row0 = t >> 2;
    const int row1 = 64 + row0;
    const int seg = t & 3;

    int mA0 = m0 + row0; if (mA0 >= M1) mA0 = M1 - 1;
    int mA1 = m0 + row1; if (mA1 >= M1) mA1 = M1 - 1;
    const unsigned short* aG0 = x1 + (size_t)mA0 * DIM + seg * 8;
    const unsigned short* aG1 = x1 + (size_t)mA1 * DIM + seg * 8;
    const bool bv0 = (row0 < COUT);
    const bool bv1 = (row1 < COUT);
    const unsigned short* bG0 = w2b + (size_t)row0 * DIM + seg * 8;
    const unsigned short* bG1 = w2b + (size_t)row1 * DIM + seg * 8;

    const int lane = t & 63;
    const int wv = t >> 6;
    const int wm = wv & 1, wn = wv >> 1;
    const int lr = lane & 15, quad = lane >> 4;

    f32x4 acc[4][4];
    #pragma unroll
    for (int i = 0; i < 4; ++i)
        #pragma unroll
        for (int j = 0; j < 4; ++j)
            acc[i][j] = (f32x4){0.f, 0.f, 0.f, 0.f};

    unsigned short* aW0 = aLds + row0 * LDT + seg * 8;
    unsigned short* aW1 = aLds + row1 * LDT + seg * 8;
    unsigned short* bW0 = bLds + row0 * LDT + seg * 8;
    unsigned short* bW1 = bLds + row1 * LDT + seg * 8;
    const int4 zero4 = {0, 0, 0, 0};

    #pragma unroll 1
    for (int k0 = 0; k0 < DIM; k0 += 32) {
        int4 va0 = *(const int4*)(aG0 + k0);
        int4 va1 = *(const int4*)(aG1 + k0);
        int4 vb0 = bv0 ? *(const int4*)(bG0 + k0) : zero4;
        int4 vb1 = bv1 ? *(const int4*)(bG1 + k0) : zero4;
        __syncthreads();
        *(int4*)aW0 = va0;
        *(int4*)aW1 = va1;
        *(int4*)bW0 = vb0;
        *(int4*)bW1 = vb1;
        __syncthreads();
        bf16x8 af[4], bfr[4];
        #pragma unroll
        for (int i = 0; i < 4; ++i)
            af[i] = *(const bf16x8*)(aLds + (wm * 64 + i * 16 + lr) * LDT + quad * 8);
        #pragma unroll
        for (int j = 0; j < 4; ++j)
            bfr[j] = *(const bf16x8*)(bLds + (wn * 64 + j * 16 + lr) * LDT + quad * 8);
        #pragma unroll
        for (int i = 0; i < 4; ++i)
            #pragma unroll
            for (int j = 0; j < 4; ++j)
                acc[i][j] = __builtin_amdgcn_mfma_f32_16x16x32_bf16(
                    af[i], bfr[j], acc[i][j], 0, 0, 0);
    }

    #pragma unroll
    for (int i = 0; i < 4; ++i) {
        const int mloc = m0 + wm * 64 + i * 16 + quad * 4;
        #pragma unroll
        for (int j = 0; j < 4; ++j) {
            const int n = wn * 64 + j * 16 + lr;
            if (n >= COUT) continue;
            const float bias = b2[n];
            #pragma unroll
            for (int r = 0; r < 4; ++r) {
                const int m = mloc + r;
                if (m < M1)
                    out[(size_t)m * COUT + n] = acc[i][j][r] + bias;
            }
        }
    }
}

// ---------------------------------------------------------------------------
extern "C" void kernel_launch(void* const* d_in, const int* in_sizes, int n_in,
                              void* d_out, int out_size, void* d_ws, size_t ws_size,
                              hipStream_t stream)
{
    const float* fmap = (const float*)d_in[0];
    const float* w1   = (const float*)d_in[1];
    const float* b1   = (const float*)d_in[2];
    const float* w2   = (const float*)d_in[3];
    const float* b2   = (const float*)d_in[4];
    float* out = (float*)d_out;

    char* ws = (char*)d_ws;
    const size_t NHWC_BYTES = (size_t)B_ * HP * HP * CIN * 2;        // 99,680,256
    const size_t W1B_BYTES  = (size_t)DIM * 9 * CIN * 2;             //  9,437,184
    const size_t W2B_BYTES  = (size_t)COUT * DIM * 2;                //    122,880
    unsigned short* nhwc = (unsigned short*)ws;
    unsigned short* w1b  = (unsigned short*)(ws + NHWC_BYTES);
    unsigned short* w2b  = (unsigned short*)(ws + NHWC_BYTES + W1B_BYTES);
    unsigned short* x1   = (unsigned short*)(ws + NHWC_BYTES + W1B_BYTES + W2B_BYTES);

    // zero padded borders (and everything else) of nhwc
    hipMemsetAsync(nhwc, 0, NHWC_BYTES, stream);

    pad_transpose<<<B_ * 37 * 4, 256, 0, stream>>>(fmap, nhwc);
    reorder_w1<<<(DIM * 9 * CIN) / 256, 256, 0, stream>>>(w1, w1b);
    cast_w2<<<(COUT * DIM + 255) / 256, 256, 0, stream>>>(w2, w2b);

    conv1_gemm<<<343 * 4, 256, 0, stream>>>(nhwc, w1b, b1, x1);
    conv2_gemm<<<343, 256, 0, stream>>>(x1, w2b, b2, out);
}

// Round 2
// 913.570 us; speedup vs baseline: 1.0299x; 1.0299x over previous
//
#include <hip/hip_runtime.h>

typedef __attribute__((ext_vector_type(8))) short bf16x8;
typedef __attribute__((ext_vector_type(4))) float f32x4;

#define B_    32
#define CIN   1024
#define H_    37
#define W_    37
#define HP    39          // padded spatial
#define DIM   512
#define COUT  120
#define M1    43808       // B*H*W

// async global->LDS DMA, 16 B per lane, dest = wave-uniform base + lane*16
#define GLOAD_LDS(g, l) __builtin_amdgcn_global_load_lds( \
    (const __attribute__((address_space(1))) void*)(g),   \
    (__attribute__((address_space(3))) void*)(l), 16, 0, 0)

// fp32 -> bf16 round-to-nearest-even
__device__ __forceinline__ unsigned short f2bf(float f) {
    unsigned int u = __float_as_uint(f);
    unsigned int r = 0x7fffu + ((u >> 16) & 1u);
    return (unsigned short)((u + r) >> 16);
}

// ---------------------------------------------------------------------------
// K0: NCHW fp32 -> padded NHWC bf16  [32][39][39][1024], interior only
// (borders pre-zeroed by hipMemsetAsync). One block = (b, y, 256-ci tile).
// ---------------------------------------------------------------------------
__global__ __launch_bounds__(256) void pad_transpose(
    const float* __restrict__ fmap, unsigned short* __restrict__ nhwc)
{
    __shared__ float lds[37 * 257];  // [xx][cl], +1 pad breaks bank conflicts
    const int t = threadIdx.x;
    const int bid = blockIdx.x;
    const int citile = bid & 3;
    const int rest = bid >> 2;
    const int y = rest % 37;
    const int b = rest / 37;
    const int ci0 = citile * 256;

    const float* src = fmap + ((size_t)(b * CIN + ci0)) * (H_ * W_) + y * W_;
    #pragma unroll 1
    for (int k = 0; k < 37; ++k) {
        unsigned int flat = (unsigned)(k * 256 + t);   // = cl*37 + xx
        unsigned int cl = flat / 37u;
        unsigned int xx = flat - cl * 37u;
        lds[xx * 257 + cl] = src[(size_t)cl * (H_ * W_) + xx];
    }
    __syncthreads();
    unsigned short* dst = nhwc + ((size_t)(b * HP + y + 1) * HP + 1) * CIN + ci0;
    #pragma unroll 1
    for (int k = 0; k < 37; ++k) {
        unsigned int flat = (unsigned)(k * 256 + t);
        unsigned int xx = flat >> 8;       // /256
        unsigned int cl = flat & 255u;
        dst[(size_t)xx * CIN + cl] = f2bf(lds[xx * 257 + cl]);
    }
}

// ---------------------------------------------------------------------------
// K1: w1 [512][1024][3][3] fp32 -> [512][9][1024] bf16 via LDS transpose.
// One block per n: coalesced read of 9216 floats, coalesced write of 9216 bf16.
// ---------------------------------------------------------------------------
__global__ __launch_bounds__(256) void reorder_w1(
    const float* __restrict__ w1, unsigned short* __restrict__ w1b)
{
    __shared__ unsigned short lds[9216];
    const int n = blockIdx.x;
    const int t = threadIdx.x;
    const float* src = w1 + (size_t)n * 9216;
    #pragma unroll 1
    for (int i = 0; i < 36; ++i) {
        int flat = i * 256 + t;            // = ci*9 + kk
        int ci = flat / 9;
        int kk = flat - ci * 9;
        lds[kk * 1024 + ci] = f2bf(src[flat]);
    }
    __syncthreads();
    unsigned short* dst = w1b + (size_t)n * 9216;
    #pragma unroll 1
    for (int i = 0; i < 36; ++i) {
        int idx = i * 256 + t;
        dst[idx] = lds[idx];
    }
}

// ---------------------------------------------------------------------------
// K2: w2 [120][512] fp32 -> bf16 (layout already [n][k])
// ---------------------------------------------------------------------------
__global__ __launch_bounds__(256) void cast_w2(
    const float* __restrict__ w2, unsigned short* __restrict__ w2b)
{
    int g = blockIdx.x * 256 + threadIdx.x;
    if (g < COUT * DIM) w2b[g] = f2bf(w2[g]);
}

// ---------------------------------------------------------------------------
// K3: implicit GEMM conv3x3: M=43808, N=512, K=9216, BM=BN=128, BK=32
// m97-style: global_load_lds width-16 staging, unpadded [128][32] LDS tiles,
// 2-barrier K-loop. Fused +b1, clip[0,6], store bf16 x1[m][512].
// ---------------------------------------------------------------------------
__global__ __launch_bounds__(256, 2) void conv1_gemm(
    const unsigned short* __restrict__ nhwc,
    const unsigned short* __restrict__ w1b,
    const float* __restrict__ b1,
    unsigned short* __restrict__ x1)
{
    __shared__ unsigned short aLds[128 * 32];
    __shared__ unsigned short bLds[128 * 32];

    const int t = threadIdx.x;
    const int mtile = blockIdx.x >> 2;     // 343 tiles
    const int ntile = blockIdx.x & 3;      // 4 tiles
    const int m0 = mtile * 128;
    const int n0 = ntile * 128;

    const int w = t >> 6;                  // wave id 0..3
    const int l = t & 63;
    const int rowc = l >> 2;               // 0..15 (row within DMA call)
    const int seg = l & 3;                 // 16B segment within 64B row
    const int rowA0 = w * 32 + rowc;       // DMA call 0 rows
    const int rowA1 = rowA0 + 16;          // DMA call 1 rows

    // wave-uniform LDS bases: wave w owns rows [32w, 32w+32)
    unsigned short* aB0 = aLds + w * 1024;       // 32 rows * 32 elems
    unsigned short* aB1 = aB0 + 512;             // +16 rows
    unsigned short* bB0 = bLds + w * 1024;
    unsigned short* bB1 = bB0 + 512;

    int mA0 = m0 + rowA0; if (mA0 >= M1) mA0 = M1 - 1;
    int mA1 = m0 + rowA1; if (mA1 >= M1) mA1 = M1 - 1;
    int bi0 = mA0 / 1369, rr0 = mA0 % 1369;
    int bi1 = mA1 / 1369, rr1 = mA1 % 1369;
    const int pos0 = (bi0 * HP + rr0 / 37) * HP + rr0 % 37;
    const int pos1 = (bi1 * HP + rr1 / 37) * HP + rr1 % 37;

    const unsigned short* bRow0 = w1b + (size_t)(n0 + rowA0) * 9216 + seg * 8;
    const unsigned short* bRow1 = w1b + (size_t)(n0 + rowA1) * 9216 + seg * 8;

    const int wm = w & 1, wn = w >> 1;
    const int lr = l & 15, quad = l >> 4;

    f32x4 acc[4][4];
    #pragma unroll
    for (int i = 0; i < 4; ++i)
        #pragma unroll
        for (int j = 0; j < 4; ++j)
            acc[i][j] = (f32x4){0.f, 0.f, 0.f, 0.f};

    for (int kykx = 0; kykx < 9; ++kykx) {
        const int ky = kykx / 3, kx = kykx - ky * 3;
        const unsigned short* aG0 = nhwc + (((size_t)(pos0 + ky * HP + kx)) << 10) + seg * 8;
        const unsigned short* aG1 = nhwc + (((size_t)(pos1 + ky * HP + kx)) << 10) + seg * 8;
        const unsigned short* bG0 = bRow0 + kykx * 1024;
        const unsigned short* bG1 = bRow1 + kykx * 1024;
        #pragma unroll 1
        for (int ci0 = 0; ci0 < 1024; ci0 += 32) {
            __syncthreads();               // prev iter's LDS reads done
            GLOAD_LDS(aG0 + ci0, aB0);
            GLOAD_LDS(aG1 + ci0, aB1);
            GLOAD_LDS(bG0 + ci0, bB0);
            GLOAD_LDS(bG1 + ci0, bB1);
            __syncthreads();               // vmcnt(0) drain: DMA data visible
            bf16x8 af[4], bfr[4];
            #pragma unroll
            for (int i = 0; i < 4; ++i)
                af[i] = *(const bf16x8*)(aLds + (wm * 64 + i * 16 + lr) * 32 + quad * 8);
            #pragma unroll
            for (int j = 0; j < 4; ++j)
                bfr[j] = *(const bf16x8*)(bLds + (wn * 64 + j * 16 + lr) * 32 + quad * 8);
            #pragma unroll
            for (int i = 0; i < 4; ++i)
                #pragma unroll
                for (int j = 0; j < 4; ++j)
                    acc[i][j] = __builtin_amdgcn_mfma_f32_16x16x32_bf16(
                        af[i], bfr[j], acc[i][j], 0, 0, 0);
        }
    }

    // epilogue: C/D layout col=lane&15, row=quad*4+reg
    #pragma unroll
    for (int i = 0; i < 4; ++i) {
        const int mloc = m0 + wm * 64 + i * 16 + quad * 4;
        #pragma unroll
        for (int j = 0; j < 4; ++j) {
            const int n = n0 + wn * 64 + j * 16 + lr;
            const float bias = b1[n];
            #pragma unroll
            for (int r = 0; r < 4; ++r) {
                const int m = mloc + r;
                if (m < M1) {
                    float v = acc[i][j][r] + bias;
                    v = fminf(fmaxf(v, 0.f), 6.f);
                    x1[(size_t)m * DIM + n] = f2bf(v);
                }
            }
        }
    }
}

// ---------------------------------------------------------------------------
// K4: GEMM conv1x1: M=43808, N=120 (tile 128 w/ guards), K=512
// Same global_load_lds staging. out fp32 = x1 @ w2b^T + b2 -> d_out
// (NHWC-flat == reference order). B rows >=120 clamped (never stored).
// ---------------------------------------------------------------------------
__global__ __launch_bounds__(256, 2) void conv2_gemm(
    const unsigned short* __restrict__ x1,
    const unsigned short* __restrict__ w2b,
    const float* __restrict__ b2,
    float* __restrict__ out)
{
    __shared__ unsigned short aLds[128 * 32];
    __shared__ unsigned short bLds[128 * 32];

    const int t = threadIdx.x;
    const int m0 = blockIdx.x * 128;

    const int w = t >> 6;
    const int l = t & 63;
    const int rowc = l >> 2;
    const int seg = l & 3;
    const int rowA0 = w * 32 + rowc;
    const int rowA1 = rowA0 + 16;

    unsigned short* aB0 = aLds + w * 1024;
    unsigned short* aB1 = aB0 + 512;
    unsigned short* bB0 = bLds + w * 1024;
    unsigned short* bB1 = bB0 + 512;

    int mA0 = m0 + rowA0; if (mA0 >= M1) mA0 = M1 - 1;
    int mA1 = m0 + rowA1; if (mA1 >= M1) mA1 = M1 - 1;
    const unsigned short* aG0 = x1 + (size_t)mA0 * DIM + seg * 8;
    const unsigned short* aG1 = x1 + (size_t)mA1 * DIM + seg * 8;
    int nB0 = rowA0 > (COUT - 1) ? (COUT - 1) : rowA0;
    int nB1 = rowA1 > (COUT - 1) ? (COUT - 1) : rowA1;
    const unsigned short* bG0 = w2b + (size_t)nB0 * DIM + seg * 8;
    const unsigned short* bG1 = w2b + (size_t)nB1 * DIM + seg * 8;

    const int wm = w & 1, wn = w >> 1;
    const int lr = l & 15, quad = l >> 4;

    f32x4 acc[4][4];
    #pragma unroll
    for (int i = 0; i < 4; ++i)
        #pragma unroll
        for (int j = 0; j < 4; ++j)
            acc[i][j] = (f32x4){0.f, 0.f, 0.f, 0.f};

    #pragma unroll 1
    for (int k0 = 0; k0 < DIM; k0 += 32) {
        __syncthreads();
        GLOAD_LDS(aG0 + k0, aB0);
        GLOAD_LDS(aG1 + k0, aB1);
        GLOAD_LDS(bG0 + k0, bB0);
        GLOAD_LDS(bG1 + k0, bB1);
        __syncthreads();
        bf16x8 af[4], bfr[4];
        #pragma unroll
        for (int i = 0; i < 4; ++i)
            af[i] = *(const bf16x8*)(aLds + (wm * 64 + i * 16 + lr) * 32 + quad * 8);
        #pragma unroll
        for (int j = 0; j < 4; ++j)
            bfr[j] = *(const bf16x8*)(bLds + (wn * 64 + j * 16 + lr) * 32 + quad * 8);
        #pragma unroll
        for (int i = 0; i < 4; ++i)
            #pragma unroll
            for (int j = 0; j < 4; ++j)
                acc[i][j] = __builtin_amdgcn_mfma_f32_16x16x32_bf16(
                    af[i], bfr[j], acc[i][j], 0, 0, 0);
    }

    #pragma unroll
    for (int i = 0; i < 4; ++i) {
        const int mloc = m0 + wm * 64 + i * 16 + quad * 4;
        #pragma unroll
        for (int j = 0; j < 4; ++j) {
            const int n = wn * 64 + j * 16 + lr;
            if (n >= COUT) continue;
            const float bias = b2[n];
            #pragma unroll
            for (int r = 0; r < 4; ++r) {
                const int m = mloc + r;
                if (m < M1)
                    out[(size_t)m * COUT + n] = acc[i][j][r] + bias;
            }
        }
    }
}

// ---------------------------------------------------------------------------
extern "C" void kernel_launch(void* const* d_in, const int* in_sizes, int n_in,
                              void* d_out, int out_size, void* d_ws, size_t ws_size,
                              hipStream_t stream)
{
    const float* fmap = (const float*)d_in[0];
    const float* w1   = (const float*)d_in[1];
    const float* b1   = (const float*)d_in[2];
    const float* w2   = (const float*)d_in[3];
    const float* b2   = (const float*)d_in[4];
    float* out = (float*)d_out;

    char* ws = (char*)d_ws;
    const size_t NHWC_BYTES = (size_t)B_ * HP * HP * CIN * 2;        // 99,680,256
    const size_t W1B_BYTES  = (size_t)DIM * 9 * CIN * 2;             //  9,437,184
    const size_t W2B_BYTES  = (size_t)COUT * DIM * 2;                //    122,880
    unsigned short* nhwc = (unsigned short*)ws;
    unsigned short* w1b  = (unsigned short*)(ws + NHWC_BYTES);
    unsigned short* w2b  = (unsigned short*)(ws + NHWC_BYTES + W1B_BYTES);
    unsigned short* x1   = (unsigned short*)(ws + NHWC_BYTES + W1B_BYTES + W2B_BYTES);

    // zero padded borders (and everything else) of nhwc
    hipMemsetAsync(nhwc, 0, NHWC_BYTES, stream);

    pad_transpose<<<B_ * 37 * 4, 256, 0, stream>>>(fmap, nhwc);
    reorder_w1<<<DIM, 256, 0, stream>>>(w1, w1b);
    cast_w2<<<(COUT * DIM + 255) / 256, 256, 0, stream>>>(w2, w2b);

    conv1_gemm<<<343 * 4, 256, 0, stream>>>(nhwc, w1b, b1, x1);
    conv2_gemm<<<343, 256, 0, stream>>>(x1, w2b, b2, out);
}

// Round 3
// 812.150 us; speedup vs baseline: 1.1585x; 1.1249x over previous
//
#include <hip/hip_runtime.h>

typedef __attribute__((ext_vector_type(8))) short bf16x8;
typedef __attribute__((ext_vector_type(4))) float f32x4;

#define B_    32
#define CIN   1024
#define H_    37
#define W_    37
#define HP    39          // padded spatial
#define DIM   512
#define COUT  120
#define M1    43808       // B*H*W

// async global->LDS DMA, 16 B per lane, dest = wave-uniform base + lane*16
#define GLOAD_LDS(g, l) __builtin_amdgcn_global_load_lds( \
    (const __attribute__((address_space(1))) void*)(g),   \
    (__attribute__((address_space(3))) void*)(l), 16, 0, 0)

// fp32 -> bf16 round-to-nearest-even
__device__ __forceinline__ unsigned short f2bf(float f) {
    unsigned int u = __float_as_uint(f);
    unsigned int r = 0x7fffu + ((u >> 16) & 1u);
    return (unsigned short)((u + r) >> 16);
}

// ---------------------------------------------------------------------------
// K0a: zero only the border ring of nhwc [32][39][39][1024] (interior is
// fully overwritten by pad_transpose). 152 border positions per image.
// ---------------------------------------------------------------------------
__global__ __launch_bounds__(256) void zero_border(unsigned short* __restrict__ nhwc)
{
    const int g = blockIdx.x * 256 + threadIdx.x;   // 622336 threads, 8 elems each
    const int e = g * 8;
    const int img = e >> 17;                        // /(152*1024) -> no, 152*1024=155648
    // careful: 152*1024 is not a power of two; do it properly
    const int per_img = 152 * 1024;
    const int image = e / per_img;
    const int rem = e - image * per_img;
    const int posIdx = rem >> 10;
    const int ci = rem & 1023;
    int y, x;
    if (posIdx < 39)       { y = 0;  x = posIdx; }
    else if (posIdx < 78)  { y = 38; x = posIdx - 39; }
    else if (posIdx < 115) { x = 0;  y = 1 + (posIdx - 78); }
    else                   { x = 38; y = 1 + (posIdx - 115); }
    (void)img;
    unsigned short* dst = nhwc + (((size_t)(image * HP + y) * HP + x) << 10) + ci;
    *(int4*)dst = (int4){0, 0, 0, 0};
}

// ---------------------------------------------------------------------------
// K0: NCHW fp32 -> padded NHWC bf16  [32][39][39][1024], interior only.
// One block = (b, y, 256-ci tile).
// ---------------------------------------------------------------------------
__global__ __launch_bounds__(256) void pad_transpose(
    const float* __restrict__ fmap, unsigned short* __restrict__ nhwc)
{
    __shared__ float lds[37 * 257];  // [xx][cl], +1 pad breaks bank conflicts
    const int t = threadIdx.x;
    const int bid = blockIdx.x;
    const int citile = bid & 3;
    const int rest = bid >> 2;
    const int y = rest % 37;
    const int b = rest / 37;
    const int ci0 = citile * 256;

    const float* src = fmap + ((size_t)(b * CIN + ci0)) * (H_ * W_) + y * W_;
    #pragma unroll 1
    for (int k = 0; k < 37; ++k) {
        unsigned int flat = (unsigned)(k * 256 + t);   // = cl*37 + xx
        unsigned int cl = flat / 37u;
        unsigned int xx = flat - cl * 37u;
        lds[xx * 257 + cl] = src[(size_t)cl * (H_ * W_) + xx];
    }
    __syncthreads();
    unsigned short* dst = nhwc + ((size_t)(b * HP + y + 1) * HP + 1) * CIN + ci0;
    #pragma unroll 1
    for (int k = 0; k < 37; ++k) {
        unsigned int flat = (unsigned)(k * 256 + t);
        unsigned int xx = flat >> 8;       // /256
        unsigned int cl = flat & 255u;
        dst[(size_t)xx * CIN + cl] = f2bf(lds[xx * 257 + cl]);
    }
}

// ---------------------------------------------------------------------------
// K1: w1 [512][1024][3][3] fp32 -> [512][9][1024] bf16 via LDS transpose.
// ---------------------------------------------------------------------------
__global__ __launch_bounds__(256) void reorder_w1(
    const float* __restrict__ w1, unsigned short* __restrict__ w1b)
{
    __shared__ unsigned short lds[9216];
    const int n = blockIdx.x;
    const int t = threadIdx.x;
    const float* src = w1 + (size_t)n * 9216;
    #pragma unroll 1
    for (int i = 0; i < 36; ++i) {
        int flat = i * 256 + t;            // = ci*9 + kk
        int ci = flat / 9;
        int kk = flat - ci * 9;
        lds[kk * 1024 + ci] = f2bf(src[flat]);
    }
    __syncthreads();
    unsigned short* dst = w1b + (size_t)n * 9216;
    #pragma unroll 1
    for (int i = 0; i < 36; ++i) {
        int idx = i * 256 + t;
        dst[idx] = lds[idx];
    }
}

// ---------------------------------------------------------------------------
// K2: w2 [120][512] fp32 -> bf16 (layout already [n][k])
// ---------------------------------------------------------------------------
__global__ __launch_bounds__(256) void cast_w2(
    const float* __restrict__ w2, unsigned short* __restrict__ w2b)
{
    int g = blockIdx.x * 256 + threadIdx.x;
    if (g < COUT * DIM) w2b[g] = f2bf(w2[g]);
}

// ---------------------------------------------------------------------------
// K3: implicit GEMM conv3x3: M=43808, N=512, K=9216, BM=BN=128, BK=64
// (two side-by-side [128][32] sub-tiles -> 32 MFMAs per barrier drain).
// XCD swizzle: 4 sibling n-tile blocks of one m-tile land on one XCD.
// Fused +b1, clip[0,6], store bf16 x1[m][512].
// ---------------------------------------------------------------------------
__global__ __launch_bounds__(256, 2) void conv1_gemm(
    const unsigned short* __restrict__ nhwc,
    const unsigned short* __restrict__ w1b,
    const float* __restrict__ b1,
    unsigned short* __restrict__ x1)
{
    __shared__ unsigned short aLds[2 * 128 * 32];   // [kc][row][32]
    __shared__ unsigned short bLds[2 * 128 * 32];

    // XCD-aware swizzle (blockIdx % 8 -> XCD round-robin heuristic):
    // each XCD owns 43 consecutive m-tiles x 4 n-tiles.
    const int bid = blockIdx.x;                    // 1376 blocks
    const int xcd = bid & 7;
    const int u = bid >> 3;                        // 0..171
    const int mtile = xcd * 43 + (u >> 2);         // 0..343
    const int ntile = u & 3;
    if (mtile >= 343) return;                      // uniform exit, pre-barrier
    const int m0 = mtile * 128;
    const int n0 = ntile * 128;

    const int t = threadIdx.x;
    const int w = t >> 6;                  // wave id 0..3
    const int l = t & 63;
    const int rowc = l >> 2;               // 0..15 (row within DMA call)
    const int seg = l & 3;                 // 16B segment within 64B row
    const int rowA0 = w * 32 + rowc;       // DMA rows group 0
    const int rowA1 = rowA0 + 16;          // DMA rows group 1

    int mA0 = m0 + rowA0; if (mA0 >= M1) mA0 = M1 - 1;
    int mA1 = m0 + rowA1; if (mA1 >= M1) mA1 = M1 - 1;
    int bi0 = mA0 / 1369, rr0 = mA0 % 1369;
    int bi1 = mA1 / 1369, rr1 = mA1 % 1369;
    const int pos0 = (bi0 * HP + rr0 / 37) * HP + rr0 % 37;
    const int pos1 = (bi1 * HP + rr1 / 37) * HP + rr1 % 37;

    const unsigned short* bRow0 = w1b + (size_t)(n0 + rowA0) * 9216 + seg * 8;
    const unsigned short* bRow1 = w1b + (size_t)(n0 + rowA1) * 9216 + seg * 8;

    const int wm = w & 1, wn = w >> 1;
    const int lr = l & 15, quad = l >> 4;

    f32x4 acc[4][4];
    #pragma unroll
    for (int i = 0; i < 4; ++i)
        #pragma unroll
        for (int j = 0; j < 4; ++j)
            acc[i][j] = (f32x4){0.f, 0.f, 0.f, 0.f};

    for (int kykx = 0; kykx < 9; ++kykx) {
        const int ky = kykx / 3, kx = kykx - ky * 3;
        const unsigned short* aG0 = nhwc + (((size_t)(pos0 + ky * HP + kx)) << 10) + seg * 8;
        const unsigned short* aG1 = nhwc + (((size_t)(pos1 + ky * HP + kx)) << 10) + seg * 8;
        const unsigned short* bG0 = bRow0 + kykx * 1024;
        const unsigned short* bG1 = bRow1 + kykx * 1024;
        #pragma unroll 1
        for (int ci0 = 0; ci0 < 1024; ci0 += 64) {
            __syncthreads();               // prev iter's LDS reads done
            GLOAD_LDS(aG0 + ci0,      aLds + w * 1024);
            GLOAD_LDS(aG1 + ci0,      aLds + w * 1024 + 512);
            GLOAD_LDS(aG0 + ci0 + 32, aLds + 4096 + w * 1024);
            GLOAD_LDS(aG1 + ci0 + 32, aLds + 4096 + w * 1024 + 512);
            GLOAD_LDS(bG0 + ci0,      bLds + w * 1024);
            GLOAD_LDS(bG1 + ci0,      bLds + w * 1024 + 512);
            GLOAD_LDS(bG0 + ci0 + 32, bLds + 4096 + w * 1024);
            GLOAD_LDS(bG1 + ci0 + 32, bLds + 4096 + w * 1024 + 512);
            __syncthreads();               // vmcnt(0) drain: DMA data visible
            #pragma unroll
            for (int kc = 0; kc < 2; ++kc) {
                bf16x8 af[4], bfr[4];
                #pragma unroll
                for (int i = 0; i < 4; ++i)
                    af[i] = *(const bf16x8*)(aLds + kc * 4096 +
                                             (wm * 64 + i * 16 + lr) * 32 + quad * 8);
                #pragma unroll
                for (int j = 0; j < 4; ++j)
                    bfr[j] = *(const bf16x8*)(bLds + kc * 4096 +
                                              (wn * 64 + j * 16 + lr) * 32 + quad * 8);
                #pragma unroll
                for (int i = 0; i < 4; ++i)
                    #pragma unroll
                    for (int j = 0; j < 4; ++j)
                        acc[i][j] = __builtin_amdgcn_mfma_f32_16x16x32_bf16(
                            af[i], bfr[j], acc[i][j], 0, 0, 0);
            }
        }
    }

    // epilogue: C/D layout col=lane&15, row=quad*4+reg
    #pragma unroll
    for (int i = 0; i < 4; ++i) {
        const int mloc = m0 + wm * 64 + i * 16 + quad * 4;
        #pragma unroll
        for (int j = 0; j < 4; ++j) {
            const int n = n0 + wn * 64 + j * 16 + lr;
            const float bias = b1[n];
            #pragma unroll
            for (int r = 0; r < 4; ++r) {
                const int m = mloc + r;
                if (m < M1) {
                    float v = acc[i][j][r] + bias;
                    v = fminf(fmaxf(v, 0.f), 6.f);
                    x1[(size_t)m * DIM + n] = f2bf(v);
                }
            }
        }
    }
}

// ---------------------------------------------------------------------------
// K4: GEMM conv1x1: M=43808, N=120 (tile 128 w/ guards), K=512, BK=64.
// out fp32 = x1 @ w2b^T + b2 -> d_out (NHWC-flat == reference order).
// ---------------------------------------------------------------------------
__global__ __launch_bounds__(256, 2) void conv2_gemm(
    const unsigned short* __restrict__ x1,
    const unsigned short* __restrict__ w2b,
    const float* __restrict__ b2,
    float* __restrict__ out)
{
    __shared__ unsigned short aLds[2 * 128 * 32];
    __shared__ unsigned short bLds[2 * 128 * 32];

    const int t = threadIdx.x;
    const int m0 = blockIdx.x * 128;

    const int w = t >> 6;
    const int l = t & 63;
    const int rowc = l >> 2;
    const int seg = l & 3;
    const int rowA0 = w * 32 + rowc;
    const int rowA1 = rowA0 + 16;

    int mA0 = m0 + rowA0; if (mA0 >= M1) mA0 = M1 - 1;
    int mA1 = m0 + rowA1; if (mA1 >= M1) mA1 = M1 - 1;
    const unsigned short* aG0 = x1 + (size_t)mA0 * DIM + seg * 8;
    const unsigned short* aG1 = x1 + (size_t)mA1 * DIM + seg * 8;
    int nB0 = rowA0 > (COUT - 1) ? (COUT - 1) : rowA0;
    int nB1 = rowA1 > (COUT - 1) ? (COUT - 1) : rowA1;
    const unsigned short* bG0 = w2b + (size_t)nB0 * DIM + seg * 8;
    const unsigned short* bG1 = w2b + (size_t)nB1 * DIM + seg * 8;

    const int wm = w & 1, wn = w >> 1;
    const int lr = l & 15, quad = l >> 4;

    f32x4 acc[4][4];
    #pragma unroll
    for (int i = 0; i < 4; ++i)
        #pragma unroll
        for (int j = 0; j < 4; ++j)
            acc[i][j] = (f32x4){0.f, 0.f, 0.f, 0.f};

    #pragma unroll 1
    for (int k0 = 0; k0 < DIM; k0 += 64) {
        __syncthreads();
        GLOAD_LDS(aG0 + k0,      aLds + w * 1024);
        GLOAD_LDS(aG1 + k0,      aLds + w * 1024 + 512);
        GLOAD_LDS(aG0 + k0 + 32, aLds + 4096 + w * 1024);
        GLOAD_LDS(aG1 + k0 + 32, aLds + 4096 + w * 1024 + 512);
        GLOAD_LDS(bG0 + k0,      bLds + w * 1024);
        GLOAD_LDS(bG1 + k0,      bLds + w * 1024 + 512);
        GLOAD_LDS(bG0 + k0 + 32, bLds + 4096 + w * 1024);
        GLOAD_LDS(bG1 + k0 + 32, bLds + 4096 + w * 1024 + 512);
        __syncthreads();
        #pragma unroll
        for (int kc = 0; kc < 2; ++kc) {
            bf16x8 af[4], bfr[4];
            #pragma unroll
            for (int i = 0; i < 4; ++i)
                af[i] = *(const bf16x8*)(aLds + kc * 4096 +
                                         (wm * 64 + i * 16 + lr) * 32 + quad * 8);
            #pragma unroll
            for (int j = 0; j < 4; ++j)
                bfr[j] = *(const bf16x8*)(bLds + kc * 4096 +
                                          (wn * 64 + j * 16 + lr) * 32 + quad * 8);
            #pragma unroll
            for (int i = 0; i < 4; ++i)
                #pragma unroll
                for (int j = 0; j < 4; ++j)
                    acc[i][j] = __builtin_amdgcn_mfma_f32_16x16x32_bf16(
                        af[i], bfr[j], acc[i][j], 0, 0, 0);
        }
    }

    #pragma unroll
    for (int i = 0; i < 4; ++i) {
        const int mloc = m0 + wm * 64 + i * 16 + quad * 4;
        #pragma unroll
        for (int j = 0; j < 4; ++j) {
            const int n = wn * 64 + j * 16 + lr;
            if (n >= COUT) continue;
            const float bias = b2[n];
            #pragma unroll
            for (int r = 0; r < 4; ++r) {
                const int m = mloc + r;
                if (m < M1)
                    out[(size_t)m * COUT + n] = acc[i][j][r] + bias;
            }
        }
    }
}

// ---------------------------------------------------------------------------
extern "C" void kernel_launch(void* const* d_in, const int* in_sizes, int n_in,
                              void* d_out, int out_size, void* d_ws, size_t ws_size,
                              hipStream_t stream)
{
    const float* fmap = (const float*)d_in[0];
    const float* w1   = (const float*)d_in[1];
    const float* b1   = (const float*)d_in[2];
    const float* w2   = (const float*)d_in[3];
    const float* b2   = (const float*)d_in[4];
    float* out = (float*)d_out;

    char* ws = (char*)d_ws;
    const size_t NHWC_BYTES = (size_t)B_ * HP * HP * CIN * 2;        // 99,680,256
    const size_t W1B_BYTES  = (size_t)DIM * 9 * CIN * 2;             //  9,437,184
    const size_t W2B_BYTES  = (size_t)COUT * DIM * 2;                //    122,880
    unsigned short* nhwc = (unsigned short*)ws;
    unsigned short* w1b  = (unsigned short*)(ws + NHWC_BYTES);
    unsigned short* w2b  = (unsigned short*)(ws + NHWC_BYTES + W1B_BYTES);
    unsigned short* x1   = (unsigned short*)(ws + NHWC_BYTES + W1B_BYTES + W2B_BYTES);

    zero_border<<<2431, 256, 0, stream>>>(nhwc);
    pad_transpose<<<B_ * 37 * 4, 256, 0, stream>>>(fmap, nhwc);
    reorder_w1<<<DIM, 256, 0, stream>>>(w1, w1b);
    cast_w2<<<(COUT * DIM + 255) / 256, 256, 0, stream>>>(w2, w2b);

    conv1_gemm<<<344 * 4, 256, 0, stream>>>(nhwc, w1b, b1, x1);
    conv2_gemm<<<343, 256, 0, stream>>>(x1, w2b, b2, out);
}